// Round 5
// baseline (447.138 us; speedup 1.0000x reference)
//
#include <hip/hip_runtime.h>
#include <hip/hip_bf16.h>

// Lukasiewicz t-norm feature expansion, write-BW-bound (~365 MB out).
//   out[:, 0:16]    = x
//   out[:, 16:136]  = max(x[a]+x[b] - 1, 0)        (a,b)   lex combos of 16
//   out[:, 136:696] = max(x[a]+x[b]+x[c] - 2, 0)   (a,b,c) lex combos of 16
//
// R5: lane = row, combos compile-time (zero loads per output). Column chunks
// of 16 quads (64 cols). LDS row stride 17 quads -> both the write pattern
// (lane l, quad q: slot (l+q)%8) and the transposed read pattern
// (r=4i+(lane>>4), q=lane&15: slot (r+q)%8) are perfect 8-phase,
// conflict-free. Store instructions cover 4 consecutive rows x 256-B
// contiguous segments. Only lgkmcnt(0) fences (no vmcnt drain, no barrier).
//
// History: R2/R3 (per-lane runtime column table) plateaued ~369 us — theory:
// lane-divergent ds_read_b32 (random 64-lanes-over-32-banks, ~4-5-way
// conflicts x 12 reads/KB). R4 (96-B scattered store segments, r=g/6 LDS
// read) regressed to 446 us.

#define NCOLS 696
#define ROWS_PER_BLOCK 256
#define STRIDE_Q 17          // quads per lane-row region (16 + 1 pad)
#define NCHUNKS 11           // 10 x 16-quad chunks + 1 x 14-quad tail

typedef float v4f __attribute__((ext_vector_type(4)));

struct Tabs { short a[NCOLS]; short b[NCOLS]; short c[NCOLS]; };

// itertools.combinations lexicographic order; b/c = -1 marks arity 1/2.
constexpr Tabs make_tabs() {
    Tabs t{};
    int k = 0;
    for (int a = 0; a < 16; ++a) { t.a[k] = (short)a; t.b[k] = -1; t.c[k] = -1; ++k; }
    for (int a = 0; a < 16; ++a)
        for (int b = a + 1; b < 16; ++b) { t.a[k] = (short)a; t.b[k] = (short)b; t.c[k] = -1; ++k; }
    for (int a = 0; a < 16; ++a)
        for (int b = a + 1; b < 16; ++b)
            for (int c = b + 1; c < 16; ++c) { t.a[k] = (short)a; t.b[k] = (short)b; t.c[k] = (short)c; ++k; }
    return t;
}
constexpr Tabs TT = make_tabs();

// cc is compile-time under full unroll: folds to pure VALU on xv registers.
__device__ __forceinline__ float colval(const float (&xv)[16], int cc) {
    const int a = TT.a[cc], b = TT.b[cc], c = TT.c[cc];
    if (b < 0) return xv[a];
    if (c < 0) return fmaxf(xv[a] + xv[b] - 1.0f, 0.0f);
    return fmaxf(xv[a] + xv[b] + xv[c] - 2.0f, 0.0f);
}

__device__ __forceinline__ void lgkm_fence() {
    __asm__ volatile("s_waitcnt lgkmcnt(0)" ::: "memory");
}

__global__ __launch_bounds__(256, 2)
void luk_kernel(const float* __restrict__ x, float* __restrict__ out) {
    // 256 lane-rows * 17 quads * 16 B = 69.6 KB -> 2 blocks/CU.
    __shared__ v4f lds[ROWS_PER_BLOCK * STRIDE_Q];

    const int t    = threadIdx.x;
    const int wave = t >> 6;
    const int lane = t & 63;
    const size_t row = (size_t)blockIdx.x * ROWS_PER_BLOCK + t;

    // my row in registers (16 VGPRs)
    float xv[16];
    {
        const v4f* __restrict__ xr = reinterpret_cast<const v4f*>(x + row * 16);
        #pragma unroll
        for (int j = 0; j < 4; ++j) {
            const v4f v = xr[j];
            xv[4 * j + 0] = v.x; xv[4 * j + 1] = v.y;
            xv[4 * j + 2] = v.z; xv[4 * j + 3] = v.w;
        }
    }

    v4f* const myw  = &lds[t * STRIDE_Q];              // my row's write slots
    const v4f* const rb = &lds[(wave << 6) * STRIDE_Q]; // my wave's 64 rows
    float* const wbase = out +
        ((size_t)blockIdx.x * ROWS_PER_BLOCK + (size_t)(wave << 6)) * NCOLS;

    #pragma unroll
    for (int ch = 0; ch < NCHUNKS; ++ch) {
        const int Q  = (ch == NCHUNKS - 1) ? 14 : 16;  // 10*16 + 14 = 174 quads
        const int c0 = ch * 64;                        // column base

        // compute Q quads (4 cols each) for my row, park in LDS.
        // ds_write_b128: lane l, quad q -> 16B-slot (l+q)%8 -> 8-phase clean.
        #pragma unroll
        for (int q = 0; q < Q; ++q) {
            v4f o;
            o.x = colval(xv, c0 + 4 * q + 0);
            o.y = colval(xv, c0 + 4 * q + 1);
            o.z = colval(xv, c0 + 4 * q + 2);
            o.w = colval(xv, c0 + 4 * q + 3);
            myw[q] = o;
        }
        lgkm_fence();   // LDS writes visible wave-wide; vmcnt untouched

        // transposed read-back: instruction i covers rows 4i..4i+3, each a
        // contiguous 256-B segment (q = lane&15). Conflict-free 8-phase.
        #pragma unroll
        for (int i = 0; i < 16; ++i) {
            const int r = 4 * i + (lane >> 4);
            const int q = lane & 15;
            if (q < Q) {
                const v4f val = rb[r * STRIDE_Q + q];
                *reinterpret_cast<v4f*>(wbase + (size_t)r * NCOLS + c0 + 4 * q) = val;
            }
        }
        lgkm_fence();   // reads done before next chunk overwrites slots
    }
}

extern "C" void kernel_launch(void* const* d_in, const int* in_sizes, int n_in,
                              void* d_out, int out_size, void* d_ws, size_t ws_size,
                              hipStream_t stream) {
    const float* x = (const float*)d_in[0];
    float* out = (float*)d_out;
    const int nrows  = in_sizes[0] / 16;              // 131072
    const int blocks = nrows / ROWS_PER_BLOCK;        // 512, exact
    luk_kernel<<<blocks, 256, 0, stream>>>(x, out);
}

// Round 7
// 446.241 us; speedup vs baseline: 1.0020x; 1.0020x over previous
//
#include <hip/hip_runtime.h>
#include <hip/hip_bf16.h>

// Lukasiewicz t-norm feature expansion, write-BW-bound (~365 MB out).
//   out[:, 0:16]    = x
//   out[:, 16:136]  = max(x[a]+x[b] - 1, 0)        (a,b)   lex combos of 16
//   out[:, 136:696] = max(x[a]+x[b]+x[c] - 2, 0)   (a,b,c) lex combos of 16
//
// R7 = R6 minus the UB: R6 passed the aliasing LDS write/read pointers as
// __restrict__ function params -> compiler hoisted transposed ds_reads above
// the ds_writes -> NaN (read of uninitialized LDS). LDS pointers are now
// plain (no restrict); ordering enforced by s_waitcnt lgkmcnt(0) asm with
// memory clobber, which is valid once the aliasing is visible.
//
// Structure: lane = row (64 rows/block), columns split across the 4 waves
// (44/44/44/42 quads) via template<W> so all column ids are compile-time ->
// zero loads per output, pure VALU. Grid = 2048 blocks = 8 blocks/CU =
// 32 waves/CU. Wave-private LDS transpose, 4-quad chunks, stride-5 slots:
// write slot (5*lane+q)%8 and read slot (5a+qq)%8 both uniform 8-phase,
// conflict-free. 20 KB LDS/block. vmcnt never drains (no __syncthreads).
//
// History: R2/R3 (runtime col table, divergent ds_read_b32) dur 369;
// R4/R5 (register compute, 512 blocks = 8 waves/CU) dur 446/447;
// R6 NaN (restrict UB). Kernel never tops the ~240-270 us poison fills ->
// dur_us = fixed fill cost + kernel.

#define NCOLS 696

typedef float v4f __attribute__((ext_vector_type(4)));

struct Tabs { short a[NCOLS]; short b[NCOLS]; short c[NCOLS]; };

// itertools.combinations lexicographic order; b/c = -1 marks arity 1/2.
constexpr Tabs make_tabs() {
    Tabs t{};
    int k = 0;
    for (int a = 0; a < 16; ++a) { t.a[k] = (short)a; t.b[k] = -1; t.c[k] = -1; ++k; }
    for (int a = 0; a < 16; ++a)
        for (int b = a + 1; b < 16; ++b) { t.a[k] = (short)a; t.b[k] = (short)b; t.c[k] = -1; ++k; }
    for (int a = 0; a < 16; ++a)
        for (int b = a + 1; b < 16; ++b)
            for (int c = b + 1; c < 16; ++c) { t.a[k] = (short)a; t.b[k] = (short)b; t.c[k] = (short)c; ++k; }
    return t;
}
constexpr Tabs TT = make_tabs();

// cc is compile-time after full unroll: folds to 1-3 VALU on xv registers.
__device__ __forceinline__ float colval(const float (&xv)[16], int cc) {
    const int a = TT.a[cc], b = TT.b[cc], c = TT.c[cc];
    if (b < 0) return xv[a];
    if (c < 0) return fmaxf(xv[a] + xv[b] - 1.0f, 0.0f);
    return fmaxf(xv[a] + xv[b] + xv[c] - 2.0f, 0.0f);
}

__device__ __forceinline__ void lgkm_fence() {
    __asm__ volatile("s_waitcnt lgkmcnt(0)" ::: "memory");
}

// Wave W handles quads [QS, QS+QN) of the 174 quads, for its 64 rows.
// ldsw: this wave's 64-row * 5-slot LDS region (aliased write/read -- NO
// restrict here, that's the R6 bug).
template <int W>
__device__ __forceinline__ void do_quarter(const float (&xv)[16],
                                           v4f* ldsw,
                                           float* wbase, int lane) {
    const int QS = (W == 0) ? 0 : (W == 1) ? 44 : (W == 2) ? 88 : 132;
    const int QN = (W == 3) ? 42 : 44;
    const int a  = lane >> 2;   // row sub-index within a 16-row band
    const int qq = lane & 3;    // quad-in-chunk for read-back
    v4f* const myw = ldsw + lane * 5;

    #pragma unroll
    for (int ch = 0; ch * 4 < QN; ++ch) {
        const int q0 = QS + 4 * ch;                       // compile-time
        const int Qc = (QN - 4 * ch >= 4) ? 4 : QN - 4 * ch;

        // compute Qc quads (4 cols each) for my row -> wave-private LDS.
        // ds_write_b128 slot = 5*lane+q -> %8 uniform, conflict-free.
        #pragma unroll
        for (int q = 0; q < Qc; ++q) {
            v4f o;
            o.x = colval(xv, 4 * (q0 + q) + 0);
            o.y = colval(xv, 4 * (q0 + q) + 1);
            o.z = colval(xv, 4 * (q0 + q) + 2);
            o.w = colval(xv, 4 * (q0 + q) + 3);
            myw[q] = o;
        }
        lgkm_fence();   // writes visible wave-wide; vmcnt untouched

        // transposed read-back: instr i covers rows 16i..16i+15, each a
        // contiguous 64-B segment. slot = 5*(16i+a)+qq -> %8 uniform.
        #pragma unroll
        for (int i = 0; i < 4; ++i) {
            const int r = 16 * i + a;
            if (qq < Qc) {
                const v4f val = ldsw[r * 5 + qq];
                *reinterpret_cast<v4f*>(wbase + (size_t)r * NCOLS +
                                        (size_t)(q0 + qq) * 4) = val;
            }
        }
        lgkm_fence();   // reads done before next chunk overwrites slots
    }
}

__global__ __launch_bounds__(256, 8)
void luk_kernel(const float* __restrict__ x, float* __restrict__ out) {
    // 4 waves * 64 rows * 5 quad-slots * 16 B = 20 KB -> 8 blocks/CU.
    __shared__ v4f lds[4 * 64 * 5];

    const int t    = threadIdx.x;
    const int wave = t >> 6;
    const int lane = t & 63;
    const size_t row0 = (size_t)blockIdx.x * 64;

    // my row in registers (16 VGPRs); all 4 waves load the same 4 KB (L1-hot)
    float xv[16];
    {
        const v4f* xr = reinterpret_cast<const v4f*>(x + (row0 + (size_t)lane) * 16);
        #pragma unroll
        for (int j = 0; j < 4; ++j) {
            const v4f v = xr[j];
            xv[4 * j + 0] = v.x; xv[4 * j + 1] = v.y;
            xv[4 * j + 2] = v.z; xv[4 * j + 3] = v.w;
        }
    }

    v4f* const ldsw = &lds[(size_t)(wave * 64) * 5];
    float* const wbase = out + row0 * NCOLS;

    switch (wave) {
        case 0: do_quarter<0>(xv, ldsw, wbase, lane); break;
        case 1: do_quarter<1>(xv, ldsw, wbase, lane); break;
        case 2: do_quarter<2>(xv, ldsw, wbase, lane); break;
        default: do_quarter<3>(xv, ldsw, wbase, lane); break;
    }
}

extern "C" void kernel_launch(void* const* d_in, const int* in_sizes, int n_in,
                              void* d_out, int out_size, void* d_ws, size_t ws_size,
                              hipStream_t stream) {
    const float* x = (const float*)d_in[0];
    float* out = (float*)d_out;
    const int nrows  = in_sizes[0] / 16;      // 131072
    const int blocks = nrows / 64;            // 2048, exact
    luk_kernel<<<blocks, 256, 0, stream>>>(x, out);
}